// Round 5
// baseline (69.757 us; speedup 1.0000x reference)
//
#include <hip/hip_runtime.h>
#include <stdint.h>

#define N_NODES 100000
#define N_EDGES 1600000
#define IN_DIM 128
#define OUT_DIM 64

typedef __bf16    bf16x8 __attribute__((ext_vector_type(8)));
typedef float     f32x4  __attribute__((ext_vector_type(4)));
typedef _Float16  h2     __attribute__((ext_vector_type(2)));

__device__ __forceinline__ uint16_t f2bf(float f) {   // RNE
    uint32_t u = __float_as_uint(f);
    return (uint16_t)((u + 0x7fffu + ((u >> 16) & 1u)) >> 16);
}
__device__ __forceinline__ float hdot8(uint4 a, uint4 b, float c) {
#if __has_builtin(__builtin_amdgcn_fdot2)
    c = __builtin_amdgcn_fdot2(__builtin_bit_cast(h2, a.x), __builtin_bit_cast(h2, b.x), c, false);
    c = __builtin_amdgcn_fdot2(__builtin_bit_cast(h2, a.y), __builtin_bit_cast(h2, b.y), c, false);
    c = __builtin_amdgcn_fdot2(__builtin_bit_cast(h2, a.z), __builtin_bit_cast(h2, b.z), c, false);
    c = __builtin_amdgcn_fdot2(__builtin_bit_cast(h2, a.w), __builtin_bit_cast(h2, b.w), c, false);
#else
    const h2 qa[4] = {__builtin_bit_cast(h2,a.x),__builtin_bit_cast(h2,a.y),
                      __builtin_bit_cast(h2,a.z),__builtin_bit_cast(h2,a.w)};
    const h2 qb[4] = {__builtin_bit_cast(h2,b.x),__builtin_bit_cast(h2,b.y),
                      __builtin_bit_cast(h2,b.z),__builtin_bit_cast(h2,b.w)};
    #pragma unroll
    for (int i = 0; i < 4; ++i) {
        c = fmaf((float)qa[i][0], (float)qb[i][0], c);
        c = fmaf((float)qa[i][1], (float)qb[i][1], c);
    }
#endif
    return c;
}

// ---------------------------------------------------------------------------
// prep: blocks [0,6250) build row_ptr from sorted edge_src (O(N+E));
//       blocks [6250,6254) pack W into per-lane MFMA B-fragments (bf16 pairs).
// ---------------------------------------------------------------------------
__global__ __launch_bounds__(256) void prep(const int* __restrict__ src,
                                            const float* __restrict__ W,
                                            int* __restrict__ row_ptr,
                                            uint4* __restrict__ Wfrag) {
    const int b = blockIdx.x;
    if (b < N_EDGES / 256) {
        int e = b * 256 + threadIdx.x;
        int s = src[e];
        if (e == 0) {
            for (int i = 0; i <= s; ++i) row_ptr[i] = 0;
        } else {
            int sp = src[e - 1];
            for (int i = sp + 1; i <= s; ++i) row_ptr[i] = e;
        }
        if (e == N_EDGES - 1) {
            for (int i = s + 1; i <= N_NODES; ++i) row_ptr[i] = N_EDGES;
        }
    } else {
        int item = (b - N_EDGES / 256) * 256 + threadIdx.x;   // 0..1023
        if (item < 1024) {
            int f = item >> 6, lane = item & 63;
            int ct = f >> 2, ks = f & 3;
            int col = ct * 16 + (lane & 15);
            int kb  = ks * 32 + (lane >> 4) * 8;
            uint32_t u[4];
            #pragma unroll
            for (int j = 0; j < 4; ++j) {
                uint32_t lo = f2bf(W[(kb + 2 * j)     * OUT_DIM + col]);
                uint32_t hi = f2bf(W[(kb + 2 * j + 1) * OUT_DIM + col]);
                u[j] = lo | (hi << 16);
            }
            Wfrag[f * 64 + lane] = make_uint4(u[0], u[1], u[2], u[3]);
        }
    }
}

// ---------------------------------------------------------------------------
// GEMM: XPh = f16(X @ W) via mfma_f32_16x16x32_bf16. No LDS; A-frags direct
// coalesced global reads (X read exactly once); whole W lives in 64 VGPRs.
// ---------------------------------------------------------------------------
__global__ __launch_bounds__(256) void gemm_xw(const float* __restrict__ X,
                                               const uint4* __restrict__ Wfrag,
                                               _Float16* __restrict__ XPh,
                                               int nRows) {
    const int t = threadIdx.x;
    const int lane = t & 63;

    bf16x8 bfr[16];
    #pragma unroll
    for (int f = 0; f < 16; ++f)
        bfr[f] = __builtin_bit_cast(bf16x8, Wfrag[f * 64 + lane]);

    const int rowBase = blockIdx.x * 64 + (t >> 6) * 16;
    const int r  = rowBase + (lane & 15);
    const int kb = (lane >> 4) * 8;
    const bool inb = r < nRows;

    f32x4 acc[4] = {{0,0,0,0},{0,0,0,0},{0,0,0,0},{0,0,0,0}};

    #pragma unroll
    for (int ks = 0; ks < 4; ++ks) {
        float4 x0 = make_float4(0.f,0.f,0.f,0.f), x1 = x0;
        if (inb) {
            const float* p = &X[(size_t)r * IN_DIM + ks * 32 + kb];
            x0 = *(const float4*)&p[0];
            x1 = *(const float4*)&p[4];
        }
        bf16x8 a;
        a[0]=(__bf16)x0.x; a[1]=(__bf16)x0.y; a[2]=(__bf16)x0.z; a[3]=(__bf16)x0.w;
        a[4]=(__bf16)x1.x; a[5]=(__bf16)x1.y; a[6]=(__bf16)x1.z; a[7]=(__bf16)x1.w;
        #pragma unroll
        for (int ct = 0; ct < 4; ++ct)
            acc[ct] = __builtin_amdgcn_mfma_f32_16x16x32_bf16(a, bfr[ct * 4 + ks], acc[ct], 0, 0, 0);
    }

    const int orow = rowBase + (lane >> 4) * 4;
    const int ocol = lane & 15;
    #pragma unroll
    for (int ct = 0; ct < 4; ++ct) {
        #pragma unroll
        for (int rr = 0; rr < 4; ++rr) {
            int gr = orow + rr;
            if (gr < nRows) XPh[(size_t)gr * OUT_DIM + ct * 16 + ocol] = (_Float16)acc[ct][rr];
        }
    }
}

// ---------------------------------------------------------------------------
// Edge kernel: one NODE per 8-lane group (8 nodes/wave, 32/block).
// A group's 8 lanes hold the full 64-dim f16 row (16B/lane = one 128B cache
// line per gather). No cross-group epilogue: acc IS the output row.
// Depth-1 software pipeline: next dst + row gather issued before current
// compute. Wave loop runs to max degree among its 8 nodes (masked idle).
// ---------------------------------------------------------------------------
__global__ __launch_bounds__(256, 8) void agnn_edge(const _Float16* __restrict__ XPh,
                                                    const int* __restrict__ row_ptr,
                                                    const int* __restrict__ dst,
                                                    const float* __restrict__ aw,
                                                    float* __restrict__ out) {
    const int t    = threadIdx.x;
    const int lane = t & 63;
    const int g    = lane >> 3;
    const int sl   = lane & 7;
    const int node = blockIdx.x * 32 + (t >> 6) * 8 + g;   // N_NODES % 32 == 0

    const int lo = row_ptr[node];
    const int hi = row_ptr[node + 1];

    const uint4 q = *(const uint4*)&XPh[(size_t)node * OUT_DIM + sl * 8];
    float acc[8] = {0.f,0.f,0.f,0.f,0.f,0.f,0.f,0.f};

    // prologue: load edge 0 (masked groups read edge 0 of the graph — valid)
    int  e   = lo;
    bool act = e < hi;
    int  d   = dst[act ? e : 0];
    uint4 xd = *(const uint4*)&XPh[(size_t)d * OUT_DIM + sl * 8];

    while (true) {
        // prefetch next edge (hides gather latency under current compute)
        const int  en   = e + 1;
        const bool actn = en < hi;
        const int  dn   = dst[actn ? en : 0];
        const uint4 xdn = *(const uint4*)&XPh[(size_t)dn * OUT_DIM + sl * 8];

        // compute current edge
        float p = hdot8(q, xd, 0.f);
        p += __shfl_xor(p, 1);
        p += __shfl_xor(p, 2);
        p += __shfl_xor(p, 4);
        p = act ? p : 0.f;
        const h2 d0 = __builtin_bit_cast(h2, xd.x);
        const h2 d1 = __builtin_bit_cast(h2, xd.y);
        const h2 d2 = __builtin_bit_cast(h2, xd.z);
        const h2 d3 = __builtin_bit_cast(h2, xd.w);
        acc[0] = fmaf(p, (float)d0[0], acc[0]);
        acc[1] = fmaf(p, (float)d0[1], acc[1]);
        acc[2] = fmaf(p, (float)d1[0], acc[2]);
        acc[3] = fmaf(p, (float)d1[1], acc[3]);
        acc[4] = fmaf(p, (float)d2[0], acc[4]);
        acc[5] = fmaf(p, (float)d2[1], acc[5]);
        acc[6] = fmaf(p, (float)d3[0], acc[6]);
        acc[7] = fmaf(p, (float)d3[1], acc[7]);

        e = en; act = actn; xd = xdn;
        if (!__any(act)) break;
    }

    const float a = aw[0];
    float* o = &out[(size_t)node * OUT_DIM + sl * 8];
    *(float4*)&o[0] = make_float4(acc[0]*a, acc[1]*a, acc[2]*a, acc[3]*a);
    *(float4*)&o[4] = make_float4(acc[4]*a, acc[5]*a, acc[6]*a, acc[7]*a);
}

// ---------------------------------------------------------------------------
extern "C" void kernel_launch(void* const* d_in, const int* in_sizes, int n_in,
                              void* d_out, int out_size, void* d_ws, size_t ws_size,
                              hipStream_t stream) {
    const float* X   = (const float*)d_in[0];
    const float* W   = (const float*)d_in[1];
    const float* aw  = (const float*)d_in[2];
    const int*   src = (const int*)d_in[3];
    const int*   dst = (const int*)d_in[4];
    float* out = (float*)d_out;

    // ws layout: XPh f16 [N*64] | row_ptr int [N+1] | Wfrag uint4 [16*64]
    _Float16* XPh     = (_Float16*)d_ws;
    int*      row_ptr = (int*)((char*)d_ws + (size_t)N_NODES * OUT_DIM * 2);
    uint4*    Wfrag   = (uint4*)((char*)d_ws + 13200016);   // 16B-aligned

    prep<<<N_EDGES / 256 + 4, 256, 0, stream>>>(src, W, row_ptr, Wfrag);
    gemm_xw<<<(N_NODES + 63) / 64, 256, 0, stream>>>(X, Wfrag, XPh, N_NODES);
    agnn_edge<<<N_NODES / 32, 256, 0, stream>>>(XPh, row_ptr, dst, aw, out);
}